// Round 13
// baseline (480.869 us; speedup 1.0000x reference)
//
#include <hip/hip_runtime.h>
#include <math.h>

#define DIMC 1024
#define NHEADS 16
#define HDC 64
#define RANKC 512
#define NEXP 8
#define EHC 512
#define SEQC 2048
#define NBATCH 2
#define NTOK (NBATCH * SEQC)
#define EPSF 1e-6f

typedef unsigned short u16;
using bf16x8 = __attribute__((ext_vector_type(8))) short;
using f32x4 = __attribute__((ext_vector_type(4))) float;

__device__ inline u16 f2bf(float f) {
    unsigned int u = __float_as_uint(f);
    u += 0x7fff + ((u >> 16) & 1);
    return (u16)(u >> 16);
}
__device__ inline float bf2f(u16 u) { return __uint_as_float(((unsigned int)u) << 16); }

__device__ inline void gld16(const void* g, void* l) {
    __builtin_amdgcn_global_load_lds(
        (const __attribute__((address_space(1))) unsigned int*)g,
        (__attribute__((address_space(3))) unsigned int*)l, 16, 0, 0);
}

// ---------------- fused weight conversion: all 8 weights in one dispatch ----------------
__global__ __launch_bounds__(256) void convall_k(
    const float* __restrict__ wq, const float* __restrict__ wkvd,
    const float* __restrict__ wkvu, const float* __restrict__ wo,
    const float* __restrict__ sw1, const float* __restrict__ sw2,
    const float* __restrict__ ew1, const float* __restrict__ ew2,
    u16* __restrict__ wqkvd_h, u16* __restrict__ wqkvd_l,
    u16* __restrict__ wkvu_h, u16* __restrict__ wkvu_l,
    u16* __restrict__ wo_h, u16* __restrict__ wo_l,
    u16* __restrict__ sw1_b, u16* __restrict__ sw2_b,
    u16* __restrict__ ew1_b, u16* __restrict__ ew2_b) {
    size_t f = ((size_t)blockIdx.x * 256 + threadIdx.x) * 4;
    const float* src;
    u16* dh;
    u16* dl = nullptr;
    size_t local;
    if (f < 1048576) { src = wq; dh = wqkvd_h; dl = wqkvd_l; local = f; }
    else if (f < 1572864) { src = wkvd; dh = wqkvd_h + 1048576; dl = wqkvd_l + 1048576; local = f - 1048576; }
    else if (f < 2621440) { src = wkvu; dh = wkvu_h; dl = wkvu_l; local = f - 1572864; }
    else if (f < 3670016) { src = wo; dh = wo_h; dl = wo_l; local = f - 2621440; }
    else if (f < 4194304) { src = sw1; dh = sw1_b; local = f - 3670016; }
    else if (f < 4718592) { src = sw2; dh = sw2_b; local = f - 4194304; }
    else if (f < 8912896) { src = ew1; dh = ew1_b; local = f - 4718592; }
    else { src = ew2; dh = ew2_b; local = f - 8912896; }
    float4 a = *(const float4*)(src + local);
    ushort4 h = make_ushort4(f2bf(a.x), f2bf(a.y), f2bf(a.z), f2bf(a.w));
    *(ushort4*)(dh + local) = h;
    if (dl) {
        ushort4 lo = make_ushort4(f2bf(a.x - bf2f(h.x)), f2bf(a.y - bf2f(h.y)),
                                  f2bf(a.z - bf2f(h.z)), f2bf(a.w - bf2f(h.w)));
        *(ushort4*)(dl + local) = lo;
    }
}

// ---------------- RMSNorm over DIMC (pre-attention, split output) ----------------
template <bool SPLIT>
__global__ __launch_bounds__(256) void rmsnorm_k(const float* __restrict__ x,
                                                 const float* __restrict__ w,
                                                 u16* __restrict__ oh,
                                                 u16* __restrict__ ol) {
    int row = blockIdx.x;
    const float* xr = x + (size_t)row * DIMC;
    int base = threadIdx.x * 4;
    float4 xv = *(const float4*)(xr + base);
    float ss = xv.x * xv.x + xv.y * xv.y + xv.z * xv.z + xv.w * xv.w;
#pragma unroll
    for (int off = 32; off; off >>= 1) ss += __shfl_down(ss, off);
    __shared__ float sred[4];
    int wid = threadIdx.x >> 6, lane = threadIdx.x & 63;
    if (lane == 0) sred[wid] = ss;
    __syncthreads();
    float tot = sred[0] + sred[1] + sred[2] + sred[3];
    float sc = rsqrtf(tot * (1.0f / DIMC) + EPSF);
    float4 wv = *(const float4*)(w + base);
    float o0 = xv.x * sc * wv.x, o1 = xv.y * sc * wv.y;
    float o2 = xv.z * sc * wv.z, o3 = xv.w * sc * wv.w;
    ushort4 h = make_ushort4(f2bf(o0), f2bf(o1), f2bf(o2), f2bf(o3));
    size_t ob = (size_t)row * DIMC + base;
    *(ushort4*)(oh + ob) = h;
    if (SPLIT) {
        ushort4 lo = make_ushort4(f2bf(o0 - bf2f(h.x)), f2bf(o1 - bf2f(h.y)),
                                  f2bf(o2 - bf2f(h.z)), f2bf(o3 - bf2f(h.w)));
        *(ushort4*)(ol + ob) = lo;
    }
}

// ---------------- RMSNorm (FFN) fused with gate ----------------
__global__ __launch_bounds__(256) void rmsnorm_gate_k(const float* __restrict__ x,
                                                      const float* __restrict__ w,
                                                      u16* __restrict__ oh,
                                                      const float* __restrict__ gw,
                                                      float* __restrict__ topw,
                                                      int* __restrict__ topi,
                                                      float* __restrict__ plbuf) {
    int row = blockIdx.x;
    const float* xr = x + (size_t)row * DIMC;
    int base = threadIdx.x * 4;
    float4 xv = *(const float4*)(xr + base);
    float ss = xv.x * xv.x + xv.y * xv.y + xv.z * xv.z + xv.w * xv.w;
#pragma unroll
    for (int off = 32; off; off >>= 1) ss += __shfl_down(ss, off);
    __shared__ float sred[4];
    __shared__ float red[4][NEXP];
    int wid = threadIdx.x >> 6, lane = threadIdx.x & 63;
    if (lane == 0) sred[wid] = ss;
    __syncthreads();
    float tot = sred[0] + sred[1] + sred[2] + sred[3];
    float sc = rsqrtf(tot * (1.0f / DIMC) + EPSF);
    float4 wv = *(const float4*)(w + base);
    float o0 = xv.x * sc * wv.x, o1 = xv.y * sc * wv.y;
    float o2 = xv.z * sc * wv.z, o3 = xv.w * sc * wv.w;
    size_t ob = (size_t)row * DIMC + base;
    *(ushort4*)(oh + ob) = make_ushort4(f2bf(o0), f2bf(o1), f2bf(o2), f2bf(o3));
    float acc[NEXP];
#pragma unroll
    for (int e = 0; e < NEXP; e++) {
        float4 gv = *(const float4*)(gw + (size_t)e * DIMC + base);
        acc[e] = o0 * gv.x + o1 * gv.y + o2 * gv.z + o3 * gv.w;
    }
#pragma unroll
    for (int off = 32; off; off >>= 1)
#pragma unroll
        for (int e = 0; e < NEXP; e++) acc[e] += __shfl_down(acc[e], off);
    if (lane == 0)
#pragma unroll
        for (int e = 0; e < NEXP; e++) red[wid][e] = acc[e];
    __syncthreads();
    if (threadIdx.x == 0) {
        float lg[NEXP], p[NEXP];
        float mx = -1e30f;
#pragma unroll
        for (int e = 0; e < NEXP; e++) {
            lg[e] = red[0][e] + red[1][e] + red[2][e] + red[3][e];
            mx = fmaxf(mx, lg[e]);
        }
        float s = 0.f;
#pragma unroll
        for (int e = 0; e < NEXP; e++) { p[e] = __expf(lg[e] - mx); s += p[e]; }
        float invs = 1.0f / s;
#pragma unroll
        for (int e = 0; e < NEXP; e++) p[e] *= invs;
        int i0 = 0;
        for (int e = 1; e < NEXP; e++) if (p[e] > p[i0]) i0 = e;
        int i1 = (i0 == 0) ? 1 : 0;
        for (int e = 0; e < NEXP; e++) if (e != i0 && p[e] > p[i1]) i1 = e;
        float w0 = p[i0], w1 = p[i1];
        float invw = 1.0f / (w0 + w1);
        topw[row * 2] = w0 * invw;
        topw[row * 2 + 1] = w1 * invw;
        topi[row * 2] = i0;
        topi[row * 2 + 1] = i1;
#pragma unroll
        for (int e = 0; e < NEXP; e++) {
            plbuf[(size_t)e * NTOK + row] = p[e];
            plbuf[(size_t)(NEXP + e) * NTOK + row] = lg[e];
        }
    }
}

// ---------------- split-bf16 3-pass MFMA GEMM, tile 128x64, BK=64 (2 chunk-planes) ----------------
template <int EPI>
__global__ __launch_bounds__(256) void gemm_sp(const u16* __restrict__ Ah,
                                               const u16* __restrict__ Al,
                                               const u16* __restrict__ Bh,
                                               const u16* __restrict__ Bl,
                                               float* __restrict__ Cf,
                                               u16* __restrict__ Ch,
                                               u16* __restrict__ Cl,
                                               const float* __restrict__ res,
                                               int M, int K) {
    __shared__ u16 AsH[128 * 64], AsL[128 * 64];
    __shared__ u16 BsH[64 * 64], BsL[64 * 64];
    int m0 = blockIdx.x * 64, n0 = blockIdx.y * 128;
    int t = threadIdx.x;
    int w = t >> 6, l = t & 63;
    int wr = w >> 1, wc = w & 1;
    f32x4 acc[4][2];
#pragma unroll
    for (int i = 0; i < 4; i++)
#pragma unroll
        for (int j = 0; j < 2; j++) acc[i][j] = {0.f, 0.f, 0.f, 0.f};
    int lr = t >> 2, lcb = (t & 3) * 8;
    size_t aoff = (size_t)(n0 + lr) * K + lcb;
    size_t boff = (size_t)(m0 + lr) * K + lcb;
    u16* lAH = AsH + t * 8;
    u16* lAL = AsL + t * 8;
    u16* lBH = BsH + t * 8;
    u16* lBL = BsL + t * 8;
    int arow = l & 15, kblk = (l >> 4) * 8;
    for (int k0 = 0; k0 < K; k0 += 64) {
        if (k0) __syncthreads();
        gld16(Ah + aoff + k0, lAH);
        gld16(Ah + aoff + k0 + (size_t)64 * K, lAH + 2048);
        gld16(Ah + aoff + k0 + 32, lAH + 4096);
        gld16(Ah + aoff + k0 + 32 + (size_t)64 * K, lAH + 6144);
        gld16(Al + aoff + k0, lAL);
        gld16(Al + aoff + k0 + (size_t)64 * K, lAL + 2048);
        gld16(Al + aoff + k0 + 32, lAL + 4096);
        gld16(Al + aoff + k0 + 32 + (size_t)64 * K, lAL + 6144);
        gld16(Bh + boff + k0, lBH);
        gld16(Bh + boff + k0 + 32, lBH + 2048);
        gld16(Bl + boff + k0, lBL);
        gld16(Bl + boff + k0 + 32, lBL + 2048);
        __syncthreads();
#pragma unroll
        for (int c = 0; c < 2; c++) {
            int ab = c * 4096, bb = c * 2048;
            bf16x8 ah[4], al[4], bh[2], bl[2];
#pragma unroll
            for (int i = 0; i < 4; i++) {
                int ar = ab + (wr * 64 + i * 16 + arow) * 32 + kblk;
                ah[i] = *(bf16x8*)(AsH + ar);
                al[i] = *(bf16x8*)(AsL + ar);
            }
#pragma unroll
            for (int j = 0; j < 2; j++) {
                int br = bb + (wc * 32 + j * 16 + arow) * 32 + kblk;
                bh[j] = *(bf16x8*)(BsH + br);
                bl[j] = *(bf16x8*)(BsL + br);
            }
#pragma unroll
            for (int i = 0; i < 4; i++)
#pragma unroll
                for (int j = 0; j < 2; j++) {
                    acc[i][j] = __builtin_amdgcn_mfma_f32_16x16x32_bf16(ah[i], bh[j], acc[i][j], 0, 0, 0);
                    acc[i][j] = __builtin_amdgcn_mfma_f32_16x16x32_bf16(ah[i], bl[j], acc[i][j], 0, 0, 0);
                    acc[i][j] = __builtin_amdgcn_mfma_f32_16x16x32_bf16(al[i], bh[j], acc[i][j], 0, 0, 0);
                }
        }
    }
    int crow = (l >> 4) * 4, ccol = l & 15;
#pragma unroll
    for (int i = 0; i < 4; i++) {
#pragma unroll
        for (int r = 0; r < 4; r++) {
            int n = n0 + wr * 64 + i * 16 + crow + r;
#pragma unroll
            for (int j = 0; j < 2; j++) {
                int mc = m0 + wc * 32 + j * 16 + ccol;
                float vv = acc[i][j][r];
                if (EPI == 0 || EPI == 1) {
                    size_t idx = (size_t)n * M + mc;
                    if (EPI == 1) vv += res[idx];
                    Cf[idx] = vv;
                } else {  // EPI == 5
                    if (mc < 1024) {
                        Cf[(size_t)n * 1024 + mc] = vv;
                    } else {
                        size_t idx = (size_t)n * 512 + (mc - 1024);
                        u16 hi = f2bf(vv);
                        Ch[idx] = hi;
                        Cl[idx] = f2bf(vv - bf2f(hi));
                    }
                }
            }
        }
    }
}

// ---------------- single-bf16 MFMA GEMM, BK=64: final fused epilogue ----------------
__global__ __launch_bounds__(256) void gemm_fin(const u16* __restrict__ A,
                                                const u16* __restrict__ B,
                                                float* __restrict__ Cf,
                                                const float* __restrict__ res,
                                                const u16* __restrict__ yx,
                                                const float* __restrict__ tw,
                                                int M, int K) {
    __shared__ u16 As[128 * 64];
    __shared__ u16 Bs[64 * 64];
    int m0 = blockIdx.x * 64, n0 = blockIdx.y * 128;
    int t = threadIdx.x;
    int w = t >> 6, l = t & 63;
    int wr = w >> 1, wc = w & 1;
    f32x4 acc[4][2];
#pragma unroll
    for (int i = 0; i < 4; i++)
#pragma unroll
        for (int j = 0; j < 2; j++) acc[i][j] = {0.f, 0.f, 0.f, 0.f};
    int lr = t >> 2, lcb = (t & 3) * 8;
    const u16* ga = A + (size_t)(n0 + lr) * K + lcb;
    const u16* gb = B + (size_t)(m0 + lr) * K + lcb;
    u16* lA = As + t * 8;
    u16* lB = Bs + t * 8;
    int arow = l & 15, kblk = (l >> 4) * 8;
    for (int k0 = 0; k0 < K; k0 += 64) {
        if (k0) __syncthreads();
        gld16(ga + k0, lA);
        gld16(ga + k0 + (size_t)64 * K, lA + 2048);
        gld16(ga + k0 + 32, lA + 4096);
        gld16(ga + k0 + 32 + (size_t)64 * K, lA + 6144);
        gld16(gb + k0, lB);
        gld16(gb + k0 + 32, lB + 2048);
        __syncthreads();
#pragma unroll
        for (int c = 0; c < 2; c++) {
            int ab = c * 4096, bb = c * 2048;
            bf16x8 af[4], bfr[2];
#pragma unroll
            for (int i = 0; i < 4; i++)
                af[i] = *(bf16x8*)(As + ab + (wr * 64 + i * 16 + arow) * 32 + kblk);
#pragma unroll
            for (int j = 0; j < 2; j++)
                bfr[j] = *(bf16x8*)(Bs + bb + (wc * 32 + j * 16 + arow) * 32 + kblk);
#pragma unroll
            for (int i = 0; i < 4; i++)
#pragma unroll
                for (int j = 0; j < 2; j++)
                    acc[i][j] = __builtin_amdgcn_mfma_f32_16x16x32_bf16(af[i], bfr[j], acc[i][j], 0, 0, 0);
        }
    }
    int crow = (l >> 4) * 4, ccol = l & 15;
#pragma unroll
    for (int i = 0; i < 4; i++) {
#pragma unroll
        for (int r = 0; r < 4; r++) {
            int n = n0 + wr * 64 + i * 16 + crow + r;
#pragma unroll
            for (int j = 0; j < 2; j++) {
                int mc = m0 + wc * 32 + j * 16 + ccol;
                size_t idx = (size_t)n * M + mc;
                float y0 = bf2f(yx[(size_t)(2 * n) * 1024 + mc]);
                float y1 = bf2f(yx[(size_t)(2 * n + 1) * 1024 + mc]);
                Cf[idx] = acc[i][j][r] + res[idx] + tw[2 * n] * y0 + tw[2 * n + 1] * y1;
            }
        }
    }
}

// ---------------- per-head q/k RMSNorm + RoPE -> split bf16 planes ----------------
__global__ __launch_bounds__(256) void qknorm_rope_k(const float* __restrict__ q,
                                                     const float* __restrict__ kv,
                                                     const float* __restrict__ qw,
                                                     const float* __restrict__ kw,
                                                     u16* __restrict__ qhi, u16* __restrict__ qlo,
                                                     u16* __restrict__ khi, u16* __restrict__ klo) {
    int bid = blockIdx.x * 4 + (threadIdx.x >> 6);
    int head = bid & (NHEADS - 1);
    int n = bid >> 4;
    int pos = n & (SEQC - 1);
    int lane = threadIdx.x & 63;
    int i = lane >> 1;
    float inv = powf(10000.0f, -(float)(2 * i) * (1.0f / HDC));
    float ang = (float)pos * inv;
    float cs = cosf(ang), sn = sinf(ang);
    size_t off = (size_t)n * DIMC + head * HDC + lane;
    {
        float v = q[off];
        float ss = v * v;
#pragma unroll
        for (int o2 = 32; o2; o2 >>= 1) ss += __shfl_down(ss, o2);
        ss = __shfl(ss, 0);
        float sc = rsqrtf(ss * (1.0f / HDC) + EPSF);
        v = v * sc * qw[lane];
        float partner = __shfl_xor(v, 1);
        float outv = (lane & 1) ? (partner * sn + v * cs) : (v * cs - partner * sn);
        outv *= 0.125f;
        u16 hi = f2bf(outv);
        qhi[off] = hi;
        qlo[off] = f2bf(outv - bf2f(hi));
    }
    {
        float v = kv[(size_t)n * 2048 + head * HDC + lane];
        float ss = v * v;
#pragma unroll
        for (int o2 = 32; o2; o2 >>= 1) ss += __shfl_down(ss, o2);
        ss = __shfl(ss, 0);
        float sc = rsqrtf(ss * (1.0f / HDC) + EPSF);
        v = v * sc * kw[lane];
        float partner = __shfl_xor(v, 1);
        float outv = (lane & 1) ? (partner * sn + v * cs) : (v * cs - partner * sn);
        u16 hi = f2bf(outv);
        khi[off] = hi;
        klo[off] = f2bf(outv - bf2f(hi));
    }
}

// ---------------- V (kvf second half) -> V^T split-bf16 planes ----------------
__global__ __launch_bounds__(256) void transp_k(const float* __restrict__ kv,
                                                u16* __restrict__ vthi,
                                                u16* __restrict__ vtlo) {
    __shared__ float T[64][68];  // [d][j]
    int j0 = blockIdx.x * 64, head = blockIdx.y, b = blockIdx.z;
    int t = threadIdx.x;
    int jr = t >> 2, c0 = (t & 3) * 16;
    const float* src = kv + ((size_t)(b * SEQC + j0 + jr)) * 2048 + 1024 + head * HDC + c0;
#pragma unroll
    for (int u = 0; u < 4; u++) {
        float4 v4 = *(const float4*)(src + u * 4);
        T[c0 + u * 4 + 0][jr] = v4.x;
        T[c0 + u * 4 + 1][jr] = v4.y;
        T[c0 + u * 4 + 2][jr] = v4.z;
        T[c0 + u * 4 + 3][jr] = v4.w;
    }
    __syncthreads();
    int d = t >> 2, jb = (t & 3) * 16;
    size_t obase = ((size_t)((b * NHEADS + head) * HDC + d)) * SEQC + j0 + jb;
#pragma unroll
    for (int u = 0; u < 4; u++) {
        float f0 = T[d][jb + u * 4 + 0], f1 = T[d][jb + u * 4 + 1];
        float f2 = T[d][jb + u * 4 + 2], f3 = T[d][jb + u * 4 + 3];
        ushort4 h = make_ushort4(f2bf(f0), f2bf(f1), f2bf(f2), f2bf(f3));
        ushort4 lo = make_ushort4(f2bf(f0 - bf2f(h.x)), f2bf(f1 - bf2f(h.y)),
                                  f2bf(f2 - bf2f(h.z)), f2bf(f3 - bf2f(h.w)));
        *(ushort4*)(vthi + obase + u * 4) = h;
        *(ushort4*)(vtlo + obase + u * 4) = lo;
    }
}

// ---------------- per-tile attention compute (split 3-pass, swizzled LDS reads) ----------------
__device__ __forceinline__ void attn_tile(const bf16x8 (&qh)[2], const bf16x8 (&ql)[2],
                                          f32x4 (&O)[4], float (&mrow)[4], float (&lrow)[4],
                                          const u16* KHs, const u16* KLs,
                                          const u16* VHs, const u16* VLs,
                                          u16* myPH, u16* myPL,
                                          int la, int lg, int w, bool diag) {
    f32x4 S[4];
    __builtin_amdgcn_s_setprio(1);
#pragma unroll
    for (int ct = 0; ct < 4; ct++) {
        int row = ct * 16 + la;
        int sw = (row & 7) << 4;
        int a0 = ((row << 7) + (lg << 4)) ^ sw;
        int a1 = ((row << 7) + 64 + (lg << 4)) ^ sw;
        bf16x8 kh0 = *(const bf16x8*)((const char*)KHs + a0);
        bf16x8 kh1 = *(const bf16x8*)((const char*)KHs + a1);
        bf16x8 kl0 = *(const bf16x8*)((const char*)KLs + a0);
        bf16x8 kl1 = *(const bf16x8*)((const char*)KLs + a1);
        f32x4 s = {0.f, 0.f, 0.f, 0.f};
        s = __builtin_amdgcn_mfma_f32_16x16x32_bf16(qh[0], kh0, s, 0, 0, 0);
        s = __builtin_amdgcn_mfma_f32_16x16x32_bf16(qh[1], kh1, s, 0, 0, 0);
        s = __builtin_amdgcn_mfma_f32_16x16x32_bf16(qh[0], kl0, s, 0, 0, 0);
        s = __builtin_amdgcn_mfma_f32_16x16x32_bf16(qh[1], kl1, s, 0, 0, 0);
        s = __builtin_amdgcn_mfma_f32_16x16x32_bf16(ql[0], kh0, s, 0, 0, 0);
        s = __builtin_amdgcn_mfma_f32_16x16x32_bf16(ql[1], kh1, s, 0, 0, 0);
        S[ct] = s;
    }
    __builtin_amdgcn_s_setprio(0);
    if (diag) {
#pragma unroll
        for (int ct = 0; ct < 4; ct++)
#pragma unroll
            for (int r = 0; r < 4; r++)
                if (ct * 16 + la > w * 16 + lg * 4 + r) S[ct][r] = -1e30f;
    }
    float rmax[4], rsum[4];
#pragma unroll
    for (int r = 0; r < 4; r++)
        rmax[r] = fmaxf(fmaxf(S[0][r], S[1][r]), fmaxf(S[2][r], S[3][r]));
#pragma unroll
    for (int off = 1; off < 16; off <<= 1)
#pragma unroll
        for (int r = 0; r < 4; r++) rmax[r] = fmaxf(rmax[r], __shfl_xor(rmax[r], off));
    float corr[4];
#pragma unroll
    for (int r = 0; r < 4; r++) {
        float mn = fmaxf(mrow[r], rmax[r]);
        corr[r] = __expf(mrow[r] - mn);
        mrow[r] = mn;
        rsum[r] = 0.f;
    }
#pragma unroll
    for (int ct = 0; ct < 4; ct++) {
#pragma unroll
        for (int r = 0; r < 4; r++) {
            float p = __expf(S[ct][r] - mrow[r]);
            rsum[r] += p;
            u16 hi = f2bf(p);
            int pidx = (lg * 4 + r) * 68 + ct * 16 + la;
            myPH[pidx] = hi;
            myPL[pidx] = f2bf(p - bf2f(hi));
        }
    }
#pragma unroll
    for (int off = 1; off < 16; off <<= 1)
#pragma unroll
        for (int r = 0; r < 4; r++) rsum[r] += __shfl_xor(rsum[r], off);
#pragma unroll
    for (int r = 0; r < 4; r++) lrow[r] = lrow[r] * corr[r] + rsum[r];
#pragma unroll
    for (int ct = 0; ct < 4; ct++)
#pragma unroll
        for (int r = 0; r < 4; r++) O[ct][r] *= corr[r];
    asm volatile("s_waitcnt lgkmcnt(0)" ::: "memory");
    __builtin_amdgcn_sched_barrier(0);
    bf16x8 pa0 = *(const bf16x8*)(myPH + la * 68 + lg * 8);
    bf16x8 pa1 = *(const bf16x8*)(myPH + la * 68 + 32 + lg * 8);
    bf16x8 pl0 = *(const bf16x8*)(myPL + la * 68 + lg * 8);
    bf16x8 pl1 = *(const bf16x8*)(myPL + la * 68 + 32 + lg * 8);
    __builtin_amdgcn_s_setprio(1);
#pragma unroll
    for (int ct = 0; ct < 4; ct++) {
        int row = ct * 16 + la;
        int sw = (row & 7) << 4;
        int a0 = ((row << 7) + (lg << 4)) ^ sw;
        int a1 = ((row << 7) + 64 + (lg << 4)) ^ sw;
        bf16x8 vh0 = *(const bf16x8*)((const char*)VHs + a0);
        bf16x8 vh1 = *(const bf16x8*)((const char*)VHs + a1);
        bf16x8 vl0 = *(const bf16x8*)((const char*)VLs + a0);
        bf16x8 vl1 = *(const bf16x8*)((const char*)VLs + a1);
        f32x4 o = O[ct];
        o = __builtin_amdgcn_mfma_f32_16x16x32_bf16(pa0, vh0, o, 0, 0, 0);
        o = __builtin_amdgcn_mfma_f32_16x16x32_bf16(pa1, vh1, o, 0, 0, 0);
        o = __builtin_amdgcn_mfma_f32_16x16x32_bf16(pl0, vh0, o, 0, 0, 0);
        o = __builtin_amdgcn_mfma_f32_16x16x32_bf16(pl1, vh1, o, 0, 0, 0);
        o = __builtin_amdgcn_mfma_f32_16x16x32_bf16(pa0, vl0, o, 0, 0, 0);
        o = __builtin_amdgcn_mfma_f32_16x16x32_bf16(pa1, vl1, o, 0, 0, 0);
        O[ct] = o;
    }
    __builtin_amdgcn_s_setprio(0);
}

// ---------------- MFMA causal flash attention, triangle-paired, XCD-swizzled ----------------
// T14 async-STAGE: next K/V tile loaded to REGISTERS before compute, written to LDS after.
__global__ __launch_bounds__(256) void flash_k(const u16* __restrict__ qhi,
                                               const u16* __restrict__ qlo,
                                               const u16* __restrict__ khi,
                                               const u16* __restrict__ klo,
                                               const u16* __restrict__ vthi,
                                               const u16* __restrict__ vtlo,
                                               u16* __restrict__ aoh,
                                               u16* __restrict__ aol) {
    __shared__ u16 KHs[4096], KLs[4096], VHs[4096], VLs[4096];
    __shared__ u16 PH[4][16 * 68], PL[4][16 * 68];
    int id = blockIdx.x;
    int xcd = id & 7, slot = id >> 3;
    int grp = ((slot >> 4) << 3) | xcd;  // 0..31
    int pr = slot & 15;
    int head = grp & 15, b = grp >> 4;
    int qtA = pr, qtB = 31 - pr;
    int t = threadIdx.x, w = t >> 6, l = t & 63;
    int la = l & 15, lg = l >> 4;
    size_t qoffA = ((size_t)(b * SEQC + qtA * 64 + w * 16 + la)) * DIMC + head * HDC;
    size_t qoffB = ((size_t)(b * SEQC + qtB * 64 + w * 16 + la)) * DIMC + head * HDC;
    bf16x8 qhA[2], qlA[2], qhB[2], qlB[2];
    qhA[0] = *(const bf16x8*)(qhi + qoffA + lg * 8);
    qhA[1] = *(const bf16x8*)(qhi + qoffA + 32 + lg * 8);
    qlA[0] = *(const bf16x8*)(qlo + qoffA + lg * 8);
    qlA[1] = *(const bf16x8*)(qlo + qoffA + 32 + lg * 8);
    qhB[0] = *(const bf16x8*)(qhi + qoffB + lg * 8);
    qhB[1] = *(const bf16x8*)(qhi + qoffB + 32 + lg * 8);
    qlB[0] = *(const bf16x8*)(qlo + qoffB + lg * 8);
    qlB[1] = *(const bf16x8*)(qlo + qoffB + 32 + lg * 8);
    // staging source precompute (pre-swizzled, rule-21: linear dest + inv-swz src)
    int d0 = t * 16, d1 = 4096 + t * 16;
    int s0 = d0 ^ (((d0 >> 7) & 7) << 4);
    int s1 = d1 ^ (((d1 >> 7) & 7) << 4);
    int r0 = (s0 >> 7) & 63, ir0 = s0 & 127;
    int r1 = (s1 >> 7) & 63, ir1 = s1 & 127;
    size_t kb0 = ((size_t)(b * SEQC + r0) * DIMC + head * HDC) * 2 + ir0;
    size_t kb1 = ((size_t)(b * SEQC + r1) * DIMC + head * HDC) * 2 + ir1;
    size_t vb0 = ((size_t)((b * NHEADS + head) * HDC + r0)) * SEQC * 2 + ir0;
    size_t vb1 = ((size_t)((b * NHEADS + head) * HDC + r1)) * SEQC * 2 + ir1;
    const char* khp = (const char*)khi;
    const char* klp = (const char*)klo;
    const char* vhp = (const char*)vthi;
    const char* vlp = (const char*)vtlo;
    f32x4 OA[4], OB[4];
#pragma unroll
    for (int ct = 0; ct < 4; ct++) {
        OA[ct] = {0.f, 0.f, 0.f, 0.f};
        OB[ct] = {0.f, 0.f, 0.f, 0.f};
    }
    float mA[4] = {-1e30f, -1e30f, -1e30f, -1e30f};
    float lA[4] = {0.f, 0.f, 0.f, 0.f};
    float mB[4] = {-1e30f, -1e30f, -1e30f, -1e30f};
    float lB[4] = {0.f, 0.f, 0.f, 0.f};
    u16* myPH = PH[w];
    u16* myPL = PL[w];
    // per-thread linear LDS byte destinations (identical to what gld16 wrote)
    char* dKH = (char*)KHs + 16 * t;
    char* dKL = (char*)KLs + 16 * t;
    char* dVH = (char*)VHs + 16 * t;
    char* dVL = (char*)VLs + 16 * t;
    float4 rv[8];
    // load tile 0 into registers
    {
        size_t ko = 0, vo = 0;
        rv[0] = *(const float4*)(khp + kb0 + ko);
        rv[1] = *(const float4*)(khp + kb1 + ko);
        rv[2] = *(const float4*)(klp + kb0 + ko);
        rv[3] = *(const float4*)(klp + kb1 + ko);
        rv[4] = *(const float4*)(vhp + vb0 + vo);
        rv[5] = *(const float4*)(vhp + vb1 + vo);
        rv[6] = *(const float4*)(vlp + vb0 + vo);
        rv[7] = *(const float4*)(vlp + vb1 + vo);
    }
    for (int kt = 0; kt <= qtB; kt++) {
        __syncthreads();  // all waves done reading previous LDS tile
        // write staged regs -> LDS (compiler waits vmcnt for rv deps)
        *(float4*)(dKH) = rv[0];
        *(float4*)(dKH + 4096) = rv[1];
        *(float4*)(dKL) = rv[2];
        *(float4*)(dKL + 4096) = rv[3];
        *(float4*)(dVH) = rv[4];
        *(float4*)(dVH + 4096) = rv[5];
        *(float4*)(dVL) = rv[6];
        *(float4*)(dVL + 4096) = rv[7];
        // issue next tile's loads NOW; latency hides under compute below
        if (kt < qtB) {
            size_t ko = (size_t)(kt + 1) * (64 * DIMC * 2);
            size_t vo = (size_t)(kt + 1) * 128;
            rv[0] = *(const float4*)(khp + kb0 + ko);
            rv[1] = *(const float4*)(khp + kb1 + ko);
            rv[2] = *(const float4*)(klp + kb0 + ko);
            rv[3] = *(const float4*)(klp + kb1 + ko);
            rv[4] = *(const float4*)(vhp + vb0 + vo);
            rv[5] = *(const float4*)(vhp + vb1 + vo);
            rv[6] = *(const float4*)(vlp + vb0 + vo);
            rv[7] = *(const float4*)(vlp + vb1 + vo);
        }
        __syncthreads();  // LDS tile visible to all waves
        attn_tile(qhB, qlB, OB, mB, lB, KHs, KLs, VHs, VLs, myPH, myPL, la, lg, w, kt == qtB);
        if (kt <= qtA)
            attn_tile(qhA, qlA, OA, mA, lA, KHs, KLs, VHs, VLs, myPH, myPL, la, lg, w, kt == qtA);
    }
    size_t obA = ((size_t)(b * SEQC + qtA * 64 + w * 16 + lg * 4)) * DIMC + head * HDC;
    size_t obB = ((size_t)(b * SEQC + qtB * 64 + w * 16 + lg * 4)) * DIMC + head * HDC;
#pragma unroll
    for (int ct = 0; ct < 4; ct++) {
#pragma unroll
        for (int r = 0; r < 4; r++) {
            float va = OA[ct][r] / lA[r];
            size_t ia = obA + (size_t)r * DIMC + ct * 16 + la;
            u16 ha = f2bf(va);
            aoh[ia] = ha;
            aol[ia] = f2bf(va - bf2f(ha));
            float vb = OB[ct][r] / lB[r];
            size_t ib = obB + (size_t)r * DIMC + ct * 16 + la;
            u16 hb = f2bf(vb);
            aoh[ib] = hb;
            aol[ib] = f2bf(vb - bf2f(hb));
        }
    }
}

// ---------------- deterministic tree reduction of plbuf columns -> sums[16] ----------------
__global__ __launch_bounds__(256) void aux_red_k(const float* __restrict__ plbuf,
                                                 float* __restrict__ sums) {
    int col = blockIdx.x;
    const float* src = plbuf + (size_t)col * NTOK;
    float s = 0.f;
#pragma unroll
    for (int i = 0; i < NTOK / 256; i++) s += src[threadIdx.x + i * 256];
#pragma unroll
    for (int off = 32; off; off >>= 1) s += __shfl_down(s, off);
    __shared__ float red[4];
    int wid = threadIdx.x >> 6, lane = threadIdx.x & 63;
    if (lane == 0) red[wid] = s;
    __syncthreads();
    if (threadIdx.x == 0) sums[col] = red[0] + red[1] + red[2] + red[3];
}

__global__ void zero_k(int* cnt) {
    if (threadIdx.x < 8) cnt[threadIdx.x] = 0;
}

__global__ void aux_k(const float* __restrict__ sums, float* __restrict__ out) {
    if (threadIdx.x == 0) {
        const float invN = 1.0f / NTOK;
        float a = 0;
        for (int e = 0; e < NEXP; e++) a += (sums[e] * invN) * (sums[NEXP + e] * invN);
        out[0] = a * NEXP;
    }
}

// ---------------- routing: per-expert token lists ----------------
__global__ __launch_bounds__(256) void route_k(const int* __restrict__ topi,
                                               int* __restrict__ cnt,
                                               int* __restrict__ perm) {
    int n = blockIdx.x * 256 + threadIdx.x;
    if (n >= NTOK) return;
#pragma unroll
    for (int kk = 0; kk < 2; kk++) {
        int slot = n * 2 + kk;
        int e = topi[slot];
        int pos = atomicAdd(&cnt[e], 1);
        perm[e * 4096 + pos] = slot;
    }
}

// ---------------- MoE hidden + shared FFN up, BK=64 ----------------
__global__ __launch_bounds__(256) void moe_h_k(const u16* __restrict__ xb,
                                               const u16* __restrict__ w1,
                                               const u16* __restrict__ sw1b,
                                               const int* __restrict__ perm,
                                               const int* __restrict__ cnt,
                                               u16* __restrict__ hid,
                                               u16* __restrict__ s1b) {
    int e = blockIdx.z;
    bool shared = (e == NEXP);
    int count = shared ? NTOK : cnt[e];
    int n0 = blockIdx.y * 128;
    if (n0 >= count) return;
    int m0 = blockIdx.x * 64;
    __shared__ u16 As[128 * 64];
    __shared__ u16 Bs[64 * 64];
    int t = threadIdx.x;
    int w = t >> 6, l = t & 63;
    int wr = w >> 1, wc = w & 1;
    f32x4 acc[4][2];
#pragma unroll
    for (int i = 0; i < 4; i++)
#pragma unroll
        for (int j = 0; j < 2; j++) acc[i][j] = {0.f, 0.f, 0.f, 0.f};
    int lr = t >> 2, lcb = (t & 3) * 8;
    int tok0, tok1;
    if (shared) {
        tok0 = n0 + lr;
        tok1 = n0 + lr + 64;
    } else {
        tok0 = perm[e * 4096 + min(n0 + lr, count - 1)] >> 1;
        tok1 = perm[e * 4096 + min(n0 + lr + 64, count - 1)] >> 1;
    }
    const u16* ga0 = xb + (size_t)tok0 * DIMC + lcb;
    const u16* ga1 = xb + (size_t)tok1 * DIMC + lcb;
    const u16* gb = (shared ? sw1b : w1 + (size_t)e * EHC * DIMC) + (size_t)(m0 + lr) * DIMC + lcb;
    u16* lA = As + t * 8;
    u16* lB = Bs + t * 8;
    int arow = l & 15, kblk = (l >> 4) * 8;
    for (int k0 = 0; k0 < DIMC; k0 += 64) {
        if (k0) __syncthreads();
        gld16(ga0 + k0, lA);
        gld16(ga1 + k0, lA + 2048);
        gld16(ga0 + k0 + 32, lA + 4096);
        gld16(ga1 + k0 + 32, lA + 6144);
        gld16(gb + k0, lB);
        gld16(gb + k0 + 32, lB + 2048);
        __syncthreads();
#pragma unroll
        for (int c = 0; c < 2; c++) {
            int ab = c * 4096, bb = c * 2048;
            bf16x8 af[4], bfr[2];
#pragma unroll
            for (int i = 0; i < 4; i++)
                af[i] = *(bf16x8*)(As + ab + (wr * 64 + i * 16 + arow) * 32 + kblk);
#pragma unroll
            for (int j = 0; j < 2; j++)
                bfr[j] = *(bf16x8*)(Bs + bb + (wc * 32 + j * 16 + arow) * 32 + kblk);
#pragma unroll
            for (int i = 0; i < 4; i++)
#pragma unroll
                for (int j = 0; j < 2; j++)
                    acc[i][j] = __builtin_amdgcn_mfma_f32_16x16x32_bf16(af[i], bfr[j], acc[i][j], 0, 0, 0);
        }
    }
    int crow = (l >> 4) * 4, ccol = l & 15;
#pragma unroll
    for (int i = 0; i < 4; i++) {
#pragma unroll
        for (int r = 0; r < 4; r++) {
            int hrow = n0 + wr * 64 + i * 16 + crow + r;
            if (hrow >= count) continue;
            size_t dstrow = shared ? (size_t)hrow : (size_t)perm[e * 4096 + hrow];
            u16* dst = shared ? s1b : hid;
#pragma unroll
            for (int j = 0; j < 2; j++) {
                int mc = m0 + wc * 32 + j * 16 + ccol;
                float vv = acc[i][j][r];
                vv = vv / (1.0f + __expf(-vv));
                dst[dstrow * EHC + mc] = f2bf(vv);
            }
        }
    }
}

// ---------------- MoE combine, BK=64: writes yexp[slot] bf16, no atomics ----------------
__global__ __launch_bounds__(256) void moe_c_k(const u16* __restrict__ hid,
                                               const u16* __restrict__ w2,
                                               const int* __restrict__ perm,
                                               const int* __restrict__ cnt,
                                               u16* __restrict__ yexp) {
    int e = blockIdx.z;
    int count = cnt[e];
    int n0 = blockIdx.y * 128;
    if (n0 >= count) return;
    int m0 = blockIdx.x * 64;
    __shared__ u16 As[128 * 64];
    __shared__ u16 Bs[64 * 64];
    int t = threadIdx.x;
    int w = t >> 6, l = t & 63;
    int wr = w >> 1, wc = w & 1;
    f32x4 acc[4][2];
#pragma unroll
    for (int i = 0; i < 4; i++)
#pragma unroll
        for (int j = 0; j < 2; j++) acc[i][j] = {0.f, 0.f, 0.f, 0.f};
    int lr = t >> 2, lcb = (t & 3) * 8;
    int slot0 = perm[e * 4096 + min(n0 + lr, count - 1)];
    int slot1 = perm[e * 4096 + min(n0 + lr + 64, count - 1)];
    const u16* ga0 = hid + (size_t)slot0 * EHC + lcb;
    const u16* ga1 = hid + (size_t)slot1 * EHC + lcb;
    const u16* gb = w2 + (size_t)e * DIMC * EHC + (size_t)(m0 + lr) * EHC + lcb;
    u16* lA = As + t * 8;
    u16* lB = Bs + t * 8;
    int arow = l & 15, kblk = (l >> 4) * 8;
    for (int k0 = 0; k0 < EHC; k0 += 64) {
        if (k0) __syncthreads();
        gld16(ga0 + k0, lA);
        gld16(ga1 + k0, lA + 2048);
        gld16(ga0 + k0 + 32, lA + 4096);
        gld16(ga1 + k0 + 32, lA + 6144);
        gld16(gb + k0, lB);
        gld16(gb + k0 + 32, lB + 2048);
        __syncthreads();
#pragma unroll
        for (int c = 0; c < 2; c++) {
            int ab = c * 4096, bb = c * 2048;
            bf16x8 af[4], bfr[2];
#pragma unroll
            for (int i = 0; i < 4; i++)
                af[i] = *(bf16x8*)(As + ab + (wr * 64 + i * 16 + arow) * 32 + kblk);
#pragma unroll
            for (int j = 0; j < 2; j++)
                bfr[j] = *(bf16x8*)(Bs + bb + (wc * 32 + j * 16 + arow) * 32 + kblk);
#pragma unroll
            for (int i = 0; i < 4; i++)
#pragma unroll
                for (int j = 0; j < 2; j++)
                    acc[i][j] = __builtin_amdgcn_mfma_f32_16x16x32_bf16(af[i], bfr[j], acc[i][j], 0, 0, 0);
        }
    }
    int crow = (l >> 4) * 4, ccol = l & 15;
#pragma unroll
    for (int i = 0; i < 4; i++) {
#pragma unroll
        for (int r = 0; r < 4; r++) {
            int pos = n0 + wr * 64 + i * 16 + crow + r;
            if (pos >= count) continue;
            int slot = perm[e * 4096 + pos];
#pragma unroll
            for (int j = 0; j < 2; j++) {
                int mc = m0 + wc * 32 + j * 16 + ccol;
                yexp[(size_t)slot * 1024 + mc] = f2bf(acc[i][j][r]);
            }
        }
    }
}

extern "C" void kernel_launch(void* const* d_in, const int* in_sizes, int n_in,
                              void* d_out, int out_size, void* d_ws, size_t ws_size,
                              hipStream_t stream) {
    const float* x = (const float*)d_in[0];
    const float* attn_nw = (const float*)d_in[1];
    const float* ffn_nw = (const float*)d_in[2];
    const float* q_nw = (const float*)d_in[3];
    const float* k_nw = (const float*)d_in[4];
    const float* wq = (const float*)d_in[5];
    const float* wkv_down = (const float*)d_in[6];
    const float* wkv_up = (const float*)d_in[7];
    const float* wo = (const float*)d_in[8];
    const float* gate_w = (const float*)d_in[9];
    const float* sw1 = (const float*)d_in[10];
    const float* sw2 = (const float*)d_in[11];
    const float* ew1 = (const float*)d_in[12];
    const float* ew2 = (const float*)d_in[13];
    float* out = (float*)d_out;
    char* W = (char*)d_ws;
    const size_t MB = (size_t)1 << 20;

    u16* wqkvd_h = (u16*)(W + 0 * MB);
    u16* wqkvd_l = (u16*)(W + 3 * MB);
    u16* wkvu_h = (u16*)(W + 6 * MB);
    u16* wkvu_l = (u16*)(W + 8 * MB);
    u16* wo_h = (u16*)(W + 10 * MB);
    u16* wo_l = (u16*)(W + 12 * MB);
    u16* sw1_b = (u16*)(W + 14 * MB);
    u16* sw2_b = (u16*)(W + 15 * MB);
    u16* ew1_b = (u16*)(W + 16 * MB);
    u16* ew2_b = (u16*)(W + 24 * MB);
    u16* hin_h = (u16*)(W + 32 * MB);    // -> ao_h
    u16* hin_l = (u16*)(W + 40 * MB);    // -> ao_l
    float* qf = (float*)(W + 48 * MB);   // -> xm_b
    float* kvf = (float*)(W + 64 * MB);  // 32 MB combined k|v; -> h (64..80)
    u16* lat_h = (u16*)(W + 96 * MB);    // -> s1_b
    u16* lat_l = (u16*)(W + 100 * MB);
    u16* qhi = (u16*)(W + 104 * MB);     // -> hid (dead after flash)
    u16* qlo = (u16*)(W + 112 * MB);     // -> yexp (dead after flash)
    u16* khi = (u16*)(W + 120 * MB);
    u16* klo = (u16*)(W + 128 * MB);
    u16* vthi = (u16*)(W + 136 * MB);
    u16* vtlo = (u16*)(W + 144 * MB);
    float* sums = (float*)(W + 152 * MB);
    int* cnt = (int*)(W + 152 * MB + 256);
    float* topw = (float*)(W + 152 * MB + 4096);
    int* topi = (int*)(W + 152 * MB + 4096 + 32768);
    int* perm = (int*)(W + 152 * MB + 4096 + 65536);
    float* plbuf = (float*)(W + 153 * MB);
    u16* ao_h = hin_h;
    u16* ao_l = hin_l;
    u16* xm_b = (u16*)qf;
    float* h = (float*)(W + 64 * MB);
    u16* s1_b = lat_h;
    u16* hid = qhi;
    u16* yexp = qlo;

    convall_k<<<12800, 256, 0, stream>>>(wq, wkv_down, wkv_up, wo, sw1, sw2, ew1, ew2,
                                         wqkvd_h, wqkvd_l, wkvu_h, wkvu_l,
                                         wo_h, wo_l, sw1_b, sw2_b, ew1_b, ew2_b);

    rmsnorm_k<true><<<NTOK, 256, 0, stream>>>(x, attn_nw, hin_h, hin_l);
    gemm_sp<5><<<dim3(24, 32), 256, 0, stream>>>(hin_h, hin_l, wqkvd_h, wqkvd_l, qf, lat_h, lat_l, nullptr, 1024, DIMC);
    gemm_sp<0><<<dim3(32, 32), 256, 0, stream>>>(lat_h, lat_l, wkvu_h, wkvu_l, kvf, nullptr, nullptr, nullptr, 2048, RANKC);
    qknorm_rope_k<<<NTOK * NHEADS / 4, 256, 0, stream>>>(qf, kvf, q_nw, k_nw, qhi, qlo, khi, klo);
    transp_k<<<dim3(SEQC / 64, NHEADS, NBATCH), 256, 0, stream>>>(kvf, vthi, vtlo);
    flash_k<<<dim3(512), 256, 0, stream>>>(qhi, qlo, khi, klo, vthi, vtlo, ao_h, ao_l);
    gemm_sp<1><<<dim3(16, 32), 256, 0, stream>>>(ao_h, ao_l, wo_h, wo_l, h, nullptr, nullptr, x, DIMC, DIMC);
    zero_k<<<1, 64, 0, stream>>>(cnt);
    rmsnorm_gate_k<<<NTOK, 256, 0, stream>>>(h, ffn_nw, xm_b, gate_w, topw, topi, plbuf);
    aux_red_k<<<16, 256, 0, stream>>>(plbuf, sums);
    route_k<<<16, 256, 0, stream>>>(topi, cnt, perm);
    moe_h_k<<<dim3(8, 32, 9), 256, 0, stream>>>(xm_b, ew1_b, sw1_b, perm, cnt, hid, s1_b);
    moe_c_k<<<dim3(16, 32, 8), 256, 0, stream>>>(hid, ew2_b, perm, cnt, yexp);
    gemm_fin<<<dim3(16, 32), 256, 0, stream>>>(s1_b, sw2_b, out, h, yexp, topw, DIMC, EHC);
    aux_k<<<1, 64, 0, stream>>>(sums, out + 4194304);
}

// Round 14
// 395.619 us; speedup vs baseline: 1.2155x; 1.2155x over previous
//
#include <hip/hip_runtime.h>
#include <math.h>

#define DIMC 1024
#define NHEADS 16
#define HDC 64
#define RANKC 512
#define NEXP 8
#define EHC 512
#define SEQC 2048
#define NBATCH 2
#define NTOK (NBATCH * SEQC)
#define EPSF 1e-6f

typedef unsigned short u16;
using bf16x8 = __attribute__((ext_vector_type(8))) short;
using f32x4 = __attribute__((ext_vector_type(4))) float;

__device__ inline u16 f2bf(float f) {
    unsigned int u = __float_as_uint(f);
    u += 0x7fff + ((u >> 16) & 1);
    return (u16)(u >> 16);
}
__device__ inline float bf2f(u16 u) { return __uint_as_float(((unsigned int)u) << 16); }

__device__ inline void gld16(const void* g, void* l) {
    __builtin_amdgcn_global_load_lds(
        (const __attribute__((address_space(1))) unsigned int*)g,
        (__attribute__((address_space(3))) unsigned int*)l, 16, 0, 0);
}

// ---------------- fused weight conversion: all 8 weights in one dispatch ----------------
__global__ __launch_bounds__(256) void convall_k(
    const float* __restrict__ wq, const float* __restrict__ wkvd,
    const float* __restrict__ wkvu, const float* __restrict__ wo,
    const float* __restrict__ sw1, const float* __restrict__ sw2,
    const float* __restrict__ ew1, const float* __restrict__ ew2,
    u16* __restrict__ wqkvd_h, u16* __restrict__ wqkvd_l,
    u16* __restrict__ wkvu_h, u16* __restrict__ wkvu_l,
    u16* __restrict__ wo_h, u16* __restrict__ wo_l,
    u16* __restrict__ sw1_b, u16* __restrict__ sw2_b,
    u16* __restrict__ ew1_b, u16* __restrict__ ew2_b) {
    size_t f = ((size_t)blockIdx.x * 256 + threadIdx.x) * 4;
    const float* src;
    u16* dh;
    u16* dl = nullptr;
    size_t local;
    if (f < 1048576) { src = wq; dh = wqkvd_h; dl = wqkvd_l; local = f; }
    else if (f < 1572864) { src = wkvd; dh = wqkvd_h + 1048576; dl = wqkvd_l + 1048576; local = f - 1048576; }
    else if (f < 2621440) { src = wkvu; dh = wkvu_h; dl = wkvu_l; local = f - 1572864; }
    else if (f < 3670016) { src = wo; dh = wo_h; dl = wo_l; local = f - 2621440; }
    else if (f < 4194304) { src = sw1; dh = sw1_b; local = f - 3670016; }
    else if (f < 4718592) { src = sw2; dh = sw2_b; local = f - 4194304; }
    else if (f < 8912896) { src = ew1; dh = ew1_b; local = f - 4718592; }
    else { src = ew2; dh = ew2_b; local = f - 8912896; }
    float4 a = *(const float4*)(src + local);
    ushort4 h = make_ushort4(f2bf(a.x), f2bf(a.y), f2bf(a.z), f2bf(a.w));
    *(ushort4*)(dh + local) = h;
    if (dl) {
        ushort4 lo = make_ushort4(f2bf(a.x - bf2f(h.x)), f2bf(a.y - bf2f(h.y)),
                                  f2bf(a.z - bf2f(h.z)), f2bf(a.w - bf2f(h.w)));
        *(ushort4*)(dl + local) = lo;
    }
}

// ---------------- RMSNorm over DIMC (pre-attention, split output) ----------------
template <bool SPLIT>
__global__ __launch_bounds__(256) void rmsnorm_k(const float* __restrict__ x,
                                                 const float* __restrict__ w,
                                                 u16* __restrict__ oh,
                                                 u16* __restrict__ ol) {
    int row = blockIdx.x;
    const float* xr = x + (size_t)row * DIMC;
    int base = threadIdx.x * 4;
    float4 xv = *(const float4*)(xr + base);
    float ss = xv.x * xv.x + xv.y * xv.y + xv.z * xv.z + xv.w * xv.w;
#pragma unroll
    for (int off = 32; off; off >>= 1) ss += __shfl_down(ss, off);
    __shared__ float sred[4];
    int wid = threadIdx.x >> 6, lane = threadIdx.x & 63;
    if (lane == 0) sred[wid] = ss;
    __syncthreads();
    float tot = sred[0] + sred[1] + sred[2] + sred[3];
    float sc = rsqrtf(tot * (1.0f / DIMC) + EPSF);
    float4 wv = *(const float4*)(w + base);
    float o0 = xv.x * sc * wv.x, o1 = xv.y * sc * wv.y;
    float o2 = xv.z * sc * wv.z, o3 = xv.w * sc * wv.w;
    ushort4 h = make_ushort4(f2bf(o0), f2bf(o1), f2bf(o2), f2bf(o3));
    size_t ob = (size_t)row * DIMC + base;
    *(ushort4*)(oh + ob) = h;
    if (SPLIT) {
        ushort4 lo = make_ushort4(f2bf(o0 - bf2f(h.x)), f2bf(o1 - bf2f(h.y)),
                                  f2bf(o2 - bf2f(h.z)), f2bf(o3 - bf2f(h.w)));
        *(ushort4*)(ol + ob) = lo;
    }
}

// ---------------- RMSNorm (FFN) fused with gate ----------------
__global__ __launch_bounds__(256) void rmsnorm_gate_k(const float* __restrict__ x,
                                                      const float* __restrict__ w,
                                                      u16* __restrict__ oh,
                                                      const float* __restrict__ gw,
                                                      float* __restrict__ topw,
                                                      int* __restrict__ topi,
                                                      float* __restrict__ plbuf) {
    int row = blockIdx.x;
    const float* xr = x + (size_t)row * DIMC;
    int base = threadIdx.x * 4;
    float4 xv = *(const float4*)(xr + base);
    float ss = xv.x * xv.x + xv.y * xv.y + xv.z * xv.z + xv.w * xv.w;
#pragma unroll
    for (int off = 32; off; off >>= 1) ss += __shfl_down(ss, off);
    __shared__ float sred[4];
    __shared__ float red[4][NEXP];
    int wid = threadIdx.x >> 6, lane = threadIdx.x & 63;
    if (lane == 0) sred[wid] = ss;
    __syncthreads();
    float tot = sred[0] + sred[1] + sred[2] + sred[3];
    float sc = rsqrtf(tot * (1.0f / DIMC) + EPSF);
    float4 wv = *(const float4*)(w + base);
    float o0 = xv.x * sc * wv.x, o1 = xv.y * sc * wv.y;
    float o2 = xv.z * sc * wv.z, o3 = xv.w * sc * wv.w;
    size_t ob = (size_t)row * DIMC + base;
    *(ushort4*)(oh + ob) = make_ushort4(f2bf(o0), f2bf(o1), f2bf(o2), f2bf(o3));
    float acc[NEXP];
#pragma unroll
    for (int e = 0; e < NEXP; e++) {
        float4 gv = *(const float4*)(gw + (size_t)e * DIMC + base);
        acc[e] = o0 * gv.x + o1 * gv.y + o2 * gv.z + o3 * gv.w;
    }
#pragma unroll
    for (int off = 32; off; off >>= 1)
#pragma unroll
        for (int e = 0; e < NEXP; e++) acc[e] += __shfl_down(acc[e], off);
    if (lane == 0)
#pragma unroll
        for (int e = 0; e < NEXP; e++) red[wid][e] = acc[e];
    __syncthreads();
    if (threadIdx.x == 0) {
        float lg[NEXP], p[NEXP];
        float mx = -1e30f;
#pragma unroll
        for (int e = 0; e < NEXP; e++) {
            lg[e] = red[0][e] + red[1][e] + red[2][e] + red[3][e];
            mx = fmaxf(mx, lg[e]);
        }
        float s = 0.f;
#pragma unroll
        for (int e = 0; e < NEXP; e++) { p[e] = __expf(lg[e] - mx); s += p[e]; }
        float invs = 1.0f / s;
#pragma unroll
        for (int e = 0; e < NEXP; e++) p[e] *= invs;
        int i0 = 0;
        for (int e = 1; e < NEXP; e++) if (p[e] > p[i0]) i0 = e;
        int i1 = (i0 == 0) ? 1 : 0;
        for (int e = 0; e < NEXP; e++) if (e != i0 && p[e] > p[i1]) i1 = e;
        float w0 = p[i0], w1 = p[i1];
        float invw = 1.0f / (w0 + w1);
        topw[row * 2] = w0 * invw;
        topw[row * 2 + 1] = w1 * invw;
        topi[row * 2] = i0;
        topi[row * 2 + 1] = i1;
#pragma unroll
        for (int e = 0; e < NEXP; e++) {
            plbuf[(size_t)e * NTOK + row] = p[e];
            plbuf[(size_t)(NEXP + e) * NTOK + row] = lg[e];
        }
    }
}

// ---------------- split-bf16 3-pass MFMA GEMM, tile 128x64, BK=64 (2 chunk-planes) ----------------
template <int EPI>
__global__ __launch_bounds__(256) void gemm_sp(const u16* __restrict__ Ah,
                                               const u16* __restrict__ Al,
                                               const u16* __restrict__ Bh,
                                               const u16* __restrict__ Bl,
                                               float* __restrict__ Cf,
                                               u16* __restrict__ Ch,
                                               u16* __restrict__ Cl,
                                               const float* __restrict__ res,
                                               int M, int K) {
    __shared__ u16 AsH[128 * 64], AsL[128 * 64];
    __shared__ u16 BsH[64 * 64], BsL[64 * 64];
    int m0 = blockIdx.x * 64, n0 = blockIdx.y * 128;
    int t = threadIdx.x;
    int w = t >> 6, l = t & 63;
    int wr = w >> 1, wc = w & 1;
    f32x4 acc[4][2];
#pragma unroll
    for (int i = 0; i < 4; i++)
#pragma unroll
        for (int j = 0; j < 2; j++) acc[i][j] = {0.f, 0.f, 0.f, 0.f};
    int lr = t >> 2, lcb = (t & 3) * 8;
    size_t aoff = (size_t)(n0 + lr) * K + lcb;
    size_t boff = (size_t)(m0 + lr) * K + lcb;
    u16* lAH = AsH + t * 8;
    u16* lAL = AsL + t * 8;
    u16* lBH = BsH + t * 8;
    u16* lBL = BsL + t * 8;
    int arow = l & 15, kblk = (l >> 4) * 8;
    for (int k0 = 0; k0 < K; k0 += 64) {
        if (k0) __syncthreads();
        gld16(Ah + aoff + k0, lAH);
        gld16(Ah + aoff + k0 + (size_t)64 * K, lAH + 2048);
        gld16(Ah + aoff + k0 + 32, lAH + 4096);
        gld16(Ah + aoff + k0 + 32 + (size_t)64 * K, lAH + 6144);
        gld16(Al + aoff + k0, lAL);
        gld16(Al + aoff + k0 + (size_t)64 * K, lAL + 2048);
        gld16(Al + aoff + k0 + 32, lAL + 4096);
        gld16(Al + aoff + k0 + 32 + (size_t)64 * K, lAL + 6144);
        gld16(Bh + boff + k0, lBH);
        gld16(Bh + boff + k0 + 32, lBH + 2048);
        gld16(Bl + boff + k0, lBL);
        gld16(Bl + boff + k0 + 32, lBL + 2048);
        __syncthreads();
#pragma unroll
        for (int c = 0; c < 2; c++) {
            int ab = c * 4096, bb = c * 2048;
            bf16x8 ah[4], al[4], bh[2], bl[2];
#pragma unroll
            for (int i = 0; i < 4; i++) {
                int ar = ab + (wr * 64 + i * 16 + arow) * 32 + kblk;
                ah[i] = *(bf16x8*)(AsH + ar);
                al[i] = *(bf16x8*)(AsL + ar);
            }
#pragma unroll
            for (int j = 0; j < 2; j++) {
                int br = bb + (wc * 32 + j * 16 + arow) * 32 + kblk;
                bh[j] = *(bf16x8*)(BsH + br);
                bl[j] = *(bf16x8*)(BsL + br);
            }
#pragma unroll
            for (int i = 0; i < 4; i++)
#pragma unroll
                for (int j = 0; j < 2; j++) {
                    acc[i][j] = __builtin_amdgcn_mfma_f32_16x16x32_bf16(ah[i], bh[j], acc[i][j], 0, 0, 0);
                    acc[i][j] = __builtin_amdgcn_mfma_f32_16x16x32_bf16(ah[i], bl[j], acc[i][j], 0, 0, 0);
                    acc[i][j] = __builtin_amdgcn_mfma_f32_16x16x32_bf16(al[i], bh[j], acc[i][j], 0, 0, 0);
                }
        }
    }
    int crow = (l >> 4) * 4, ccol = l & 15;
#pragma unroll
    for (int i = 0; i < 4; i++) {
#pragma unroll
        for (int r = 0; r < 4; r++) {
            int n = n0 + wr * 64 + i * 16 + crow + r;
#pragma unroll
            for (int j = 0; j < 2; j++) {
                int mc = m0 + wc * 32 + j * 16 + ccol;
                float vv = acc[i][j][r];
                if (EPI == 0 || EPI == 1) {
                    size_t idx = (size_t)n * M + mc;
                    if (EPI == 1) vv += res[idx];
                    Cf[idx] = vv;
                } else {  // EPI == 5
                    if (mc < 1024) {
                        Cf[(size_t)n * 1024 + mc] = vv;
                    } else {
                        size_t idx = (size_t)n * 512 + (mc - 1024);
                        u16 hi = f2bf(vv);
                        Ch[idx] = hi;
                        Cl[idx] = f2bf(vv - bf2f(hi));
                    }
                }
            }
        }
    }
}

// ---------------- single-bf16 MFMA GEMM, BK=64: final fused epilogue ----------------
__global__ __launch_bounds__(256) void gemm_fin(const u16* __restrict__ A,
                                                const u16* __restrict__ B,
                                                float* __restrict__ Cf,
                                                const float* __restrict__ res,
                                                const u16* __restrict__ yx,
                                                const float* __restrict__ tw,
                                                int M, int K) {
    __shared__ u16 As[128 * 64];
    __shared__ u16 Bs[64 * 64];
    int m0 = blockIdx.x * 64, n0 = blockIdx.y * 128;
    int t = threadIdx.x;
    int w = t >> 6, l = t & 63;
    int wr = w >> 1, wc = w & 1;
    f32x4 acc[4][2];
#pragma unroll
    for (int i = 0; i < 4; i++)
#pragma unroll
        for (int j = 0; j < 2; j++) acc[i][j] = {0.f, 0.f, 0.f, 0.f};
    int lr = t >> 2, lcb = (t & 3) * 8;
    const u16* ga = A + (size_t)(n0 + lr) * K + lcb;
    const u16* gb = B + (size_t)(m0 + lr) * K + lcb;
    u16* lA = As + t * 8;
    u16* lB = Bs + t * 8;
    int arow = l & 15, kblk = (l >> 4) * 8;
    for (int k0 = 0; k0 < K; k0 += 64) {
        if (k0) __syncthreads();
        gld16(ga + k0, lA);
        gld16(ga + k0 + (size_t)64 * K, lA + 2048);
        gld16(ga + k0 + 32, lA + 4096);
        gld16(ga + k0 + 32 + (size_t)64 * K, lA + 6144);
        gld16(gb + k0, lB);
        gld16(gb + k0 + 32, lB + 2048);
        __syncthreads();
#pragma unroll
        for (int c = 0; c < 2; c++) {
            int ab = c * 4096, bb = c * 2048;
            bf16x8 af[4], bfr[2];
#pragma unroll
            for (int i = 0; i < 4; i++)
                af[i] = *(bf16x8*)(As + ab + (wr * 64 + i * 16 + arow) * 32 + kblk);
#pragma unroll
            for (int j = 0; j < 2; j++)
                bfr[j] = *(bf16x8*)(Bs + bb + (wc * 32 + j * 16 + arow) * 32 + kblk);
#pragma unroll
            for (int i = 0; i < 4; i++)
#pragma unroll
                for (int j = 0; j < 2; j++)
                    acc[i][j] = __builtin_amdgcn_mfma_f32_16x16x32_bf16(af[i], bfr[j], acc[i][j], 0, 0, 0);
        }
    }
    int crow = (l >> 4) * 4, ccol = l & 15;
#pragma unroll
    for (int i = 0; i < 4; i++) {
#pragma unroll
        for (int r = 0; r < 4; r++) {
            int n = n0 + wr * 64 + i * 16 + crow + r;
#pragma unroll
            for (int j = 0; j < 2; j++) {
                int mc = m0 + wc * 32 + j * 16 + ccol;
                size_t idx = (size_t)n * M + mc;
                float y0 = bf2f(yx[(size_t)(2 * n) * 1024 + mc]);
                float y1 = bf2f(yx[(size_t)(2 * n + 1) * 1024 + mc]);
                Cf[idx] = acc[i][j][r] + res[idx] + tw[2 * n] * y0 + tw[2 * n + 1] * y1;
            }
        }
    }
}

// ---------------- per-head q/k RMSNorm + RoPE -> split bf16 planes ----------------
__global__ __launch_bounds__(256) void qknorm_rope_k(const float* __restrict__ q,
                                                     const float* __restrict__ kv,
                                                     const float* __restrict__ qw,
                                                     const float* __restrict__ kw,
                                                     u16* __restrict__ qhi, u16* __restrict__ qlo,
                                                     u16* __restrict__ khi, u16* __restrict__ klo) {
    int bid = blockIdx.x * 4 + (threadIdx.x >> 6);
    int head = bid & (NHEADS - 1);
    int n = bid >> 4;
    int pos = n & (SEQC - 1);
    int lane = threadIdx.x & 63;
    int i = lane >> 1;
    float inv = powf(10000.0f, -(float)(2 * i) * (1.0f / HDC));
    float ang = (float)pos * inv;
    float cs = cosf(ang), sn = sinf(ang);
    size_t off = (size_t)n * DIMC + head * HDC + lane;
    {
        float v = q[off];
        float ss = v * v;
#pragma unroll
        for (int o2 = 32; o2; o2 >>= 1) ss += __shfl_down(ss, o2);
        ss = __shfl(ss, 0);
        float sc = rsqrtf(ss * (1.0f / HDC) + EPSF);
        v = v * sc * qw[lane];
        float partner = __shfl_xor(v, 1);
        float outv = (lane & 1) ? (partner * sn + v * cs) : (v * cs - partner * sn);
        outv *= 0.125f;
        u16 hi = f2bf(outv);
        qhi[off] = hi;
        qlo[off] = f2bf(outv - bf2f(hi));
    }
    {
        float v = kv[(size_t)n * 2048 + head * HDC + lane];
        float ss = v * v;
#pragma unroll
        for (int o2 = 32; o2; o2 >>= 1) ss += __shfl_down(ss, o2);
        ss = __shfl(ss, 0);
        float sc = rsqrtf(ss * (1.0f / HDC) + EPSF);
        v = v * sc * kw[lane];
        float partner = __shfl_xor(v, 1);
        float outv = (lane & 1) ? (partner * sn + v * cs) : (v * cs - partner * sn);
        u16 hi = f2bf(outv);
        khi[off] = hi;
        klo[off] = f2bf(outv - bf2f(hi));
    }
}

// ---------------- V (kvf second half) -> V^T split-bf16 planes ----------------
__global__ __launch_bounds__(256) void transp_k(const float* __restrict__ kv,
                                                u16* __restrict__ vthi,
                                                u16* __restrict__ vtlo) {
    __shared__ float T[64][68];  // [d][j]
    int j0 = blockIdx.x * 64, head = blockIdx.y, b = blockIdx.z;
    int t = threadIdx.x;
    int jr = t >> 2, c0 = (t & 3) * 16;
    const float* src = kv + ((size_t)(b * SEQC + j0 + jr)) * 2048 + 1024 + head * HDC + c0;
#pragma unroll
    for (int u = 0; u < 4; u++) {
        float4 v4 = *(const float4*)(src + u * 4);
        T[c0 + u * 4 + 0][jr] = v4.x;
        T[c0 + u * 4 + 1][jr] = v4.y;
        T[c0 + u * 4 + 2][jr] = v4.z;
        T[c0 + u * 4 + 3][jr] = v4.w;
    }
    __syncthreads();
    int d = t >> 2, jb = (t & 3) * 16;
    size_t obase = ((size_t)((b * NHEADS + head) * HDC + d)) * SEQC + j0 + jb;
#pragma unroll
    for (int u = 0; u < 4; u++) {
        float f0 = T[d][jb + u * 4 + 0], f1 = T[d][jb + u * 4 + 1];
        float f2 = T[d][jb + u * 4 + 2], f3 = T[d][jb + u * 4 + 3];
        ushort4 h = make_ushort4(f2bf(f0), f2bf(f1), f2bf(f2), f2bf(f3));
        ushort4 lo = make_ushort4(f2bf(f0 - bf2f(h.x)), f2bf(f1 - bf2f(h.y)),
                                  f2bf(f2 - bf2f(h.z)), f2bf(f3 - bf2f(h.w)));
        *(ushort4*)(vthi + obase + u * 4) = h;
        *(ushort4*)(vtlo + obase + u * 4) = lo;
    }
}

// ---------------- per-tile attention compute (split 3-pass, swizzled LDS reads) ----------------
__device__ __forceinline__ void attn_tile(const bf16x8 (&qh)[2], const bf16x8 (&ql)[2],
                                          f32x4 (&O)[4], float (&mrow)[4], float (&lrow)[4],
                                          const u16* KHs, const u16* KLs,
                                          const u16* VHs, const u16* VLs,
                                          u16* myPH, u16* myPL,
                                          int la, int lg, int w, bool diag) {
    f32x4 S[4];
    __builtin_amdgcn_s_setprio(1);
#pragma unroll
    for (int ct = 0; ct < 4; ct++) {
        int row = ct * 16 + la;
        int sw = (row & 7) << 4;
        int a0 = ((row << 7) + (lg << 4)) ^ sw;
        int a1 = ((row << 7) + 64 + (lg << 4)) ^ sw;
        bf16x8 kh0 = *(const bf16x8*)((const char*)KHs + a0);
        bf16x8 kh1 = *(const bf16x8*)((const char*)KHs + a1);
        bf16x8 kl0 = *(const bf16x8*)((const char*)KLs + a0);
        bf16x8 kl1 = *(const bf16x8*)((const char*)KLs + a1);
        f32x4 s = {0.f, 0.f, 0.f, 0.f};
        s = __builtin_amdgcn_mfma_f32_16x16x32_bf16(qh[0], kh0, s, 0, 0, 0);
        s = __builtin_amdgcn_mfma_f32_16x16x32_bf16(qh[1], kh1, s, 0, 0, 0);
        s = __builtin_amdgcn_mfma_f32_16x16x32_bf16(qh[0], kl0, s, 0, 0, 0);
        s = __builtin_amdgcn_mfma_f32_16x16x32_bf16(qh[1], kl1, s, 0, 0, 0);
        s = __builtin_amdgcn_mfma_f32_16x16x32_bf16(ql[0], kh0, s, 0, 0, 0);
        s = __builtin_amdgcn_mfma_f32_16x16x32_bf16(ql[1], kh1, s, 0, 0, 0);
        S[ct] = s;
    }
    __builtin_amdgcn_s_setprio(0);
    if (diag) {
#pragma unroll
        for (int ct = 0; ct < 4; ct++)
#pragma unroll
            for (int r = 0; r < 4; r++)
                if (ct * 16 + la > w * 16 + lg * 4 + r) S[ct][r] = -1e30f;
    }
    float rmax[4], rsum[4];
#pragma unroll
    for (int r = 0; r < 4; r++)
        rmax[r] = fmaxf(fmaxf(S[0][r], S[1][r]), fmaxf(S[2][r], S[3][r]));
#pragma unroll
    for (int off = 1; off < 16; off <<= 1)
#pragma unroll
        for (int r = 0; r < 4; r++) rmax[r] = fmaxf(rmax[r], __shfl_xor(rmax[r], off));
    float corr[4];
#pragma unroll
    for (int r = 0; r < 4; r++) {
        float mn = fmaxf(mrow[r], rmax[r]);
        corr[r] = __expf(mrow[r] - mn);
        mrow[r] = mn;
        rsum[r] = 0.f;
    }
#pragma unroll
    for (int ct = 0; ct < 4; ct++) {
#pragma unroll
        for (int r = 0; r < 4; r++) {
            float p = __expf(S[ct][r] - mrow[r]);
            rsum[r] += p;
            u16 hi = f2bf(p);
            int pidx = (lg * 4 + r) * 68 + ct * 16 + la;
            myPH[pidx] = hi;
            myPL[pidx] = f2bf(p - bf2f(hi));
        }
    }
#pragma unroll
    for (int off = 1; off < 16; off <<= 1)
#pragma unroll
        for (int r = 0; r < 4; r++) rsum[r] += __shfl_xor(rsum[r], off);
#pragma unroll
    for (int r = 0; r < 4; r++) lrow[r] = lrow[r] * corr[r] + rsum[r];
#pragma unroll
    for (int ct = 0; ct < 4; ct++)
#pragma unroll
        for (int r = 0; r < 4; r++) O[ct][r] *= corr[r];
    asm volatile("s_waitcnt lgkmcnt(0)" ::: "memory");
    __builtin_amdgcn_sched_barrier(0);
    bf16x8 pa0 = *(const bf16x8*)(myPH + la * 68 + lg * 8);
    bf16x8 pa1 = *(const bf16x8*)(myPH + la * 68 + 32 + lg * 8);
    bf16x8 pl0 = *(const bf16x8*)(myPL + la * 68 + lg * 8);
    bf16x8 pl1 = *(const bf16x8*)(myPL + la * 68 + 32 + lg * 8);
    __builtin_amdgcn_s_setprio(1);
#pragma unroll
    for (int ct = 0; ct < 4; ct++) {
        int row = ct * 16 + la;
        int sw = (row & 7) << 4;
        int a0 = ((row << 7) + (lg << 4)) ^ sw;
        int a1 = ((row << 7) + 64 + (lg << 4)) ^ sw;
        bf16x8 vh0 = *(const bf16x8*)((const char*)VHs + a0);
        bf16x8 vh1 = *(const bf16x8*)((const char*)VHs + a1);
        bf16x8 vl0 = *(const bf16x8*)((const char*)VLs + a0);
        bf16x8 vl1 = *(const bf16x8*)((const char*)VLs + a1);
        f32x4 o = O[ct];
        o = __builtin_amdgcn_mfma_f32_16x16x32_bf16(pa0, vh0, o, 0, 0, 0);
        o = __builtin_amdgcn_mfma_f32_16x16x32_bf16(pa1, vh1, o, 0, 0, 0);
        o = __builtin_amdgcn_mfma_f32_16x16x32_bf16(pl0, vh0, o, 0, 0, 0);
        o = __builtin_amdgcn_mfma_f32_16x16x32_bf16(pl1, vh1, o, 0, 0, 0);
        o = __builtin_amdgcn_mfma_f32_16x16x32_bf16(pa0, vl0, o, 0, 0, 0);
        o = __builtin_amdgcn_mfma_f32_16x16x32_bf16(pa1, vl1, o, 0, 0, 0);
        O[ct] = o;
    }
    __builtin_amdgcn_s_setprio(0);
}

// ---------------- MFMA causal flash attention, triangle-paired, XCD-swizzled ----------------
// (round-12 form: gld16 staging — the reg-staged T14 variant spilled to scratch and regressed)
__global__ __launch_bounds__(256) void flash_k(const u16* __restrict__ qhi,
                                               const u16* __restrict__ qlo,
                                               const u16* __restrict__ khi,
                                               const u16* __restrict__ klo,
                                               const u16* __restrict__ vthi,
                                               const u16* __restrict__ vtlo,
                                               u16* __restrict__ aoh,
                                               u16* __restrict__ aol) {
    __shared__ u16 KHs[4096], KLs[4096], VHs[4096], VLs[4096];
    __shared__ u16 PH[4][16 * 68], PL[4][16 * 68];
    int id = blockIdx.x;
    int xcd = id & 7, slot = id >> 3;
    int grp = ((slot >> 4) << 3) | xcd;  // 0..31
    int pr = slot & 15;
    int head = grp & 15, b = grp >> 4;
    int qtA = pr, qtB = 31 - pr;
    int t = threadIdx.x, w = t >> 6, l = t & 63;
    int la = l & 15, lg = l >> 4;
    size_t qoffA = ((size_t)(b * SEQC + qtA * 64 + w * 16 + la)) * DIMC + head * HDC;
    size_t qoffB = ((size_t)(b * SEQC + qtB * 64 + w * 16 + la)) * DIMC + head * HDC;
    bf16x8 qhA[2], qlA[2], qhB[2], qlB[2];
    qhA[0] = *(const bf16x8*)(qhi + qoffA + lg * 8);
    qhA[1] = *(const bf16x8*)(qhi + qoffA + 32 + lg * 8);
    qlA[0] = *(const bf16x8*)(qlo + qoffA + lg * 8);
    qlA[1] = *(const bf16x8*)(qlo + qoffA + 32 + lg * 8);
    qhB[0] = *(const bf16x8*)(qhi + qoffB + lg * 8);
    qhB[1] = *(const bf16x8*)(qhi + qoffB + 32 + lg * 8);
    qlB[0] = *(const bf16x8*)(qlo + qoffB + lg * 8);
    qlB[1] = *(const bf16x8*)(qlo + qoffB + 32 + lg * 8);
    int d0 = t * 16, d1 = 4096 + t * 16;
    int s0 = d0 ^ (((d0 >> 7) & 7) << 4);
    int s1 = d1 ^ (((d1 >> 7) & 7) << 4);
    int r0 = (s0 >> 7) & 63, ir0 = s0 & 127;
    int r1 = (s1 >> 7) & 63, ir1 = s1 & 127;
    size_t kb0 = ((size_t)(b * SEQC + r0) * DIMC + head * HDC) * 2 + ir0;
    size_t kb1 = ((size_t)(b * SEQC + r1) * DIMC + head * HDC) * 2 + ir1;
    size_t vb0 = ((size_t)((b * NHEADS + head) * HDC + r0)) * SEQC * 2 + ir0;
    size_t vb1 = ((size_t)((b * NHEADS + head) * HDC + r1)) * SEQC * 2 + ir1;
    const char* khp = (const char*)khi;
    const char* klp = (const char*)klo;
    const char* vhp = (const char*)vthi;
    const char* vlp = (const char*)vtlo;
    f32x4 OA[4], OB[4];
#pragma unroll
    for (int ct = 0; ct < 4; ct++) {
        OA[ct] = {0.f, 0.f, 0.f, 0.f};
        OB[ct] = {0.f, 0.f, 0.f, 0.f};
    }
    float mA[4] = {-1e30f, -1e30f, -1e30f, -1e30f};
    float lA[4] = {0.f, 0.f, 0.f, 0.f};
    float mB[4] = {-1e30f, -1e30f, -1e30f, -1e30f};
    float lB[4] = {0.f, 0.f, 0.f, 0.f};
    u16* myPH = PH[w];
    u16* myPL = PL[w];
    for (int kt = 0; kt <= qtB; kt++) {
        __syncthreads();
        size_t ko = (size_t)kt * (64 * DIMC * 2);
        size_t vo = (size_t)kt * 128;
        gld16(khp + kb0 + ko, KHs + t * 8);
        gld16(khp + kb1 + ko, KHs + t * 8 + 2048);
        gld16(klp + kb0 + ko, KLs + t * 8);
        gld16(klp + kb1 + ko, KLs + t * 8 + 2048);
        gld16(vhp + vb0 + vo, VHs + t * 8);
        gld16(vhp + vb1 + vo, VHs + t * 8 + 2048);
        gld16(vlp + vb0 + vo, VLs + t * 8);
        gld16(vlp + vb1 + vo, VLs + t * 8 + 2048);
        __syncthreads();
        attn_tile(qhB, qlB, OB, mB, lB, KHs, KLs, VHs, VLs, myPH, myPL, la, lg, w, kt == qtB);
        if (kt <= qtA)
            attn_tile(qhA, qlA, OA, mA, lA, KHs, KLs, VHs, VLs, myPH, myPL, la, lg, w, kt == qtA);
    }
    size_t obA = ((size_t)(b * SEQC + qtA * 64 + w * 16 + lg * 4)) * DIMC + head * HDC;
    size_t obB = ((size_t)(b * SEQC + qtB * 64 + w * 16 + lg * 4)) * DIMC + head * HDC;
#pragma unroll
    for (int ct = 0; ct < 4; ct++) {
#pragma unroll
        for (int r = 0; r < 4; r++) {
            float va = OA[ct][r] / lA[r];
            size_t ia = obA + (size_t)r * DIMC + ct * 16 + la;
            u16 ha = f2bf(va);
            aoh[ia] = ha;
            aol[ia] = f2bf(va - bf2f(ha));
            float vb = OB[ct][r] / lB[r];
            size_t ib = obB + (size_t)r * DIMC + ct * 16 + la;
            u16 hb = f2bf(vb);
            aoh[ib] = hb;
            aol[ib] = f2bf(vb - bf2f(hb));
        }
    }
}

// ---------------- deterministic tree reduction of plbuf columns -> sums[16] ----------------
__global__ __launch_bounds__(256) void aux_red_k(const float* __restrict__ plbuf,
                                                 float* __restrict__ sums) {
    int col = blockIdx.x;
    const float* src = plbuf + (size_t)col * NTOK;
    float s = 0.f;
#pragma unroll
    for (int i = 0; i < NTOK / 256; i++) s += src[threadIdx.x + i * 256];
#pragma unroll
    for (int off = 32; off; off >>= 1) s += __shfl_down(s, off);
    __shared__ float red[4];
    int wid = threadIdx.x >> 6, lane = threadIdx.x & 63;
    if (lane == 0) red[wid] = s;
    __syncthreads();
    if (threadIdx.x == 0) sums[col] = red[0] + red[1] + red[2] + red[3];
}

__global__ void aux_k(const float* __restrict__ sums, float* __restrict__ out) {
    if (threadIdx.x == 0) {
        const float invN = 1.0f / NTOK;
        float a = 0;
        for (int e = 0; e < NEXP; e++) a += (sums[e] * invN) * (sums[NEXP + e] * invN);
        out[0] = a * NEXP;
    }
}

// ---------------- routing: single block, LDS counters (replaces zero_k + route_k) ----------------
__global__ __launch_bounds__(256) void route_k(const int* __restrict__ topi,
                                               int* __restrict__ cnt,
                                               int* __restrict__ perm) {
    __shared__ int lcnt[NEXP];
    if (threadIdx.x < NEXP) lcnt[threadIdx.x] = 0;
    __syncthreads();
    for (int i = 0; i < NTOK / 256; i++) {
        int n = i * 256 + threadIdx.x;
#pragma unroll
        for (int kk = 0; kk < 2; kk++) {
            int slot = n * 2 + kk;
            int e = topi[slot];
            int pos = atomicAdd(&lcnt[e], 1);
            perm[e * 4096 + pos] = slot;
        }
    }
    __syncthreads();
    if (threadIdx.x < NEXP) cnt[threadIdx.x] = lcnt[threadIdx.x];
}

// ---------------- MoE hidden + shared FFN up, BK=64 ----------------
__global__ __launch_bounds__(256) void moe_h_k(const u16* __restrict__ xb,
                                               const u16* __restrict__ w1,
                                               const u16* __restrict__ sw1b,
                                               const int* __restrict__ perm,
                                               const int* __restrict__ cnt,
                                               u16* __restrict__ hid,
                                               u16* __restrict__ s1b) {
    int e = blockIdx.z;
    bool shared = (e == NEXP);
    int count = shared ? NTOK : cnt[e];
    int n0 = blockIdx.y * 128;
    if (n0 >= count) return;
    int m0 = blockIdx.x * 64;
    __shared__ u16 As[128 * 64];
    __shared__ u16 Bs[64 * 64];
    int t = threadIdx.x;
    int w = t >> 6, l = t & 63;
    int wr = w >> 1, wc = w & 1;
    f32x4 acc[4][2];
#pragma unroll
    for (int i = 0; i < 4; i++)
#pragma unroll
        for (int j = 0; j < 2; j++) acc[i][j] = {0.f, 0.f, 0.f, 0.f};
    int lr = t >> 2, lcb = (t & 3) * 8;
    int tok0, tok1;
    if (shared) {
        tok0 = n0 + lr;
        tok1 = n0 + lr + 64;
    } else {
        tok0 = perm[e * 4096 + min(n0 + lr, count - 1)] >> 1;
        tok1 = perm[e * 4096 + min(n0 + lr + 64, count - 1)] >> 1;
    }
    const u16* ga0 = xb + (size_t)tok0 * DIMC + lcb;
    const u16* ga1 = xb + (size_t)tok1 * DIMC + lcb;
    const u16* gb = (shared ? sw1b : w1 + (size_t)e * EHC * DIMC) + (size_t)(m0 + lr) * DIMC + lcb;
    u16* lA = As + t * 8;
    u16* lB = Bs + t * 8;
    int arow = l & 15, kblk = (l >> 4) * 8;
    for (int k0 = 0; k0 < DIMC; k0 += 64) {
        if (k0) __syncthreads();
        gld16(ga0 + k0, lA);
        gld16(ga1 + k0, lA + 2048);
        gld16(ga0 + k0 + 32, lA + 4096);
        gld16(ga1 + k0 + 32, lA + 6144);
        gld16(gb + k0, lB);
        gld16(gb + k0 + 32, lB + 2048);
        __syncthreads();
#pragma unroll
        for (int c = 0; c < 2; c++) {
            int ab = c * 4096, bb = c * 2048;
            bf16x8 af[4], bfr[2];
#pragma unroll
            for (int i = 0; i < 4; i++)
                af[i] = *(bf16x8*)(As + ab + (wr * 64 + i * 16 + arow) * 32 + kblk);
#pragma unroll
            for (int j = 0; j < 2; j++)
                bfr[j] = *(bf16x8*)(Bs + bb + (wc * 32 + j * 16 + arow) * 32 + kblk);
#pragma unroll
            for (int i = 0; i < 4; i++)
#pragma unroll
                for (int j = 0; j < 2; j++)
                    acc[i][j] = __builtin_amdgcn_mfma_f32_16x16x32_bf16(af[i], bfr[j], acc[i][j], 0, 0, 0);
        }
    }
    int crow = (l >> 4) * 4, ccol = l & 15;
#pragma unroll
    for (int i = 0; i < 4; i++) {
#pragma unroll
        for (int r = 0; r < 4; r++) {
            int hrow = n0 + wr * 64 + i * 16 + crow + r;
            if (hrow >= count) continue;
            size_t dstrow = shared ? (size_t)hrow : (size_t)perm[e * 4096 + hrow];
            u16* dst = shared ? s1b : hid;
#pragma unroll
            for (int j = 0; j < 2; j++) {
                int mc = m0 + wc * 32 + j * 16 + ccol;
                float vv = acc[i][j][r];
                vv = vv / (1.0f + __expf(-vv));
                dst[dstrow * EHC + mc] = f2bf(vv);
            }
        }
    }
}

// ---------------- MoE combine, BK=64: writes yexp[slot] bf16, no atomics ----------------
__global__ __launch_bounds__(256) void moe_c_k(const u16* __restrict__ hid,
                                               const u16* __restrict__ w2,
                                               const int* __restrict__ perm,
                                               const int* __restrict__ cnt,
                                               u16* __restrict__ yexp) {
    int e = blockIdx.z;
    int count = cnt[e];
    int n0 = blockIdx.y * 128;
    if (n0 >= count) return;
    int m0 = blockIdx.x * 64;
    __shared__ u16 As[128 * 64];
    __shared__ u16 Bs[64 * 64];
    int t = threadIdx.x;
    int w = t >> 6, l = t & 63;
    int wr = w >> 1, wc = w & 1;
    f32x4 acc[4][2];
#pragma unroll
    for (int i = 0; i < 4; i++)
#pragma unroll
        for (int j = 0; j < 2; j++) acc[i][j] = {0.f, 0.f, 0.f, 0.f};
    int lr = t >> 2, lcb = (t & 3) * 8;
    int slot0 = perm[e * 4096 + min(n0 + lr, count - 1)];
    int slot1 = perm[e * 4096 + min(n0 + lr + 64, count - 1)];
    const u16* ga0 = hid + (size_t)slot0 * EHC + lcb;
    const u16* ga1 = hid + (size_t)slot1 * EHC + lcb;
    const u16* gb = w2 + (size_t)e * DIMC * EHC + (size_t)(m0 + lr) * EHC + lcb;
    u16* lA = As + t * 8;
    u16* lB = Bs + t * 8;
    int arow = l & 15, kblk = (l >> 4) * 8;
    for (int k0 = 0; k0 < EHC; k0 += 64) {
        if (k0) __syncthreads();
        gld16(ga0 + k0, lA);
        gld16(ga1 + k0, lA + 2048);
        gld16(ga0 + k0 + 32, lA + 4096);
        gld16(ga1 + k0 + 32, lA + 6144);
        gld16(gb + k0, lB);
        gld16(gb + k0 + 32, lB + 2048);
        __syncthreads();
#pragma unroll
        for (int c = 0; c < 2; c++) {
            int ab = c * 4096, bb = c * 2048;
            bf16x8 af[4], bfr[2];
#pragma unroll
            for (int i = 0; i < 4; i++)
                af[i] = *(bf16x8*)(As + ab + (wr * 64 + i * 16 + arow) * 32 + kblk);
#pragma unroll
            for (int j = 0; j < 2; j++)
                bfr[j] = *(bf16x8*)(Bs + bb + (wc * 32 + j * 16 + arow) * 32 + kblk);
#pragma unroll
            for (int i = 0; i < 4; i++)
#pragma unroll
                for (int j = 0; j < 2; j++)
                    acc[i][j] = __builtin_amdgcn_mfma_f32_16x16x32_bf16(af[i], bfr[j], acc[i][j], 0, 0, 0);
        }
    }
    int crow = (l >> 4) * 4, ccol = l & 15;
#pragma unroll
    for (int i = 0; i < 4; i++) {
#pragma unroll
        for (int r = 0; r < 4; r++) {
            int pos = n0 + wr * 64 + i * 16 + crow + r;
            if (pos >= count) continue;
            int slot = perm[e * 4096 + pos];
#pragma unroll
            for (int j = 0; j < 2; j++) {
                int mc = m0 + wc * 32 + j * 16 + ccol;
                yexp[(size_t)slot * 1024 + mc] = f2bf(acc[i][j][r]);
            }
        }
    }
}

extern "C" void kernel_launch(void* const* d_in, const int* in_sizes, int n_in,
                              void* d_out, int out_size, void* d_ws, size_t ws_size,
                              hipStream_t stream) {
    const float* x = (const float*)d_in[0];
    const float* attn_nw = (const float*)d_in[1];
    const float* ffn_nw = (const float*)d_in[2];
    const float* q_nw = (const float*)d_in[3];
    const float* k_nw = (const float*)d_in[4];
    const float* wq = (const float*)d_in[5];
    const float* wkv_down = (const float*)d_in[6];
    const float* wkv_up = (const float*)d_in[7];
    const float* wo = (const float*)d_in[8];
    const float* gate_w = (const float*)d_in[9];
    const float* sw1 = (const float*)d_in[10];
    const float* sw2 = (const float*)d_in[11];
    const float* ew1 = (const float*)d_in[12];
    const float* ew2 = (const float*)d_in[13];
    float* out = (float*)d_out;
    char* W = (char*)d_ws;
    const size_t MB = (size_t)1 << 20;

    u16* wqkvd_h = (u16*)(W + 0 * MB);
    u16* wqkvd_l = (u16*)(W + 3 * MB);
    u16* wkvu_h = (u16*)(W + 6 * MB);
    u16* wkvu_l = (u16*)(W + 8 * MB);
    u16* wo_h = (u16*)(W + 10 * MB);
    u16* wo_l = (u16*)(W + 12 * MB);
    u16* sw1_b = (u16*)(W + 14 * MB);
    u16* sw2_b = (u16*)(W + 15 * MB);
    u16* ew1_b = (u16*)(W + 16 * MB);
    u16* ew2_b = (u16*)(W + 24 * MB);
    u16* hin_h = (u16*)(W + 32 * MB);    // -> ao_h
    u16* hin_l = (u16*)(W + 40 * MB);    // -> ao_l
    float* qf = (float*)(W + 48 * MB);   // -> xm_b
    float* kvf = (float*)(W + 64 * MB);  // 32 MB combined k|v; -> h (64..80)
    u16* lat_h = (u16*)(W + 96 * MB);    // -> s1_b
    u16* lat_l = (u16*)(W + 100 * MB);
    u16* qhi = (u16*)(W + 104 * MB);     // -> hid (dead after flash)
    u16* qlo = (u16*)(W + 112 * MB);     // -> yexp (dead after flash)
    u16* khi = (u16*)(W + 120 * MB);
    u16* klo = (u16*)(W + 128 * MB);
    u16* vthi = (u16*)(W + 136 * MB);
    u16* vtlo = (u16*)(W + 144 * MB);
    float* sums = (float*)(W + 152 * MB);
    int* cnt = (int*)(W + 152 * MB + 256);
    float* topw = (float*)(W + 152 * MB + 4096);
    int* topi = (int*)(W + 152 * MB + 4096 + 32768);
    int* perm = (int*)(W + 152 * MB + 4096 + 65536);
    float* plbuf = (float*)(W + 153 * MB);
    u16* ao_h = hin_h;
    u16* ao_l = hin_l;
    u16* xm_b = (u16*)qf;
    float* h = (float*)(W + 64 * MB);
    u16* s1_b = lat_h;
    u16* hid = qhi;
    u16* yexp = qlo;

    convall_k<<<12800, 256, 0, stream>>>(wq, wkv_down, wkv_up, wo, sw1, sw2, ew1, ew2,
                                         wqkvd_h, wqkvd_l, wkvu_h, wkvu_l,
                                         wo_h, wo_l, sw1_b, sw2_b, ew1_b, ew2_b);

    rmsnorm_k<true><<<NTOK, 256, 0, stream>>>(x, attn_nw, hin_h, hin_l);
    gemm_sp<5><<<dim3(24, 32), 256, 0, stream>>>(hin_h, hin_l, wqkvd_h, wqkvd_l, qf, lat_h, lat_l, nullptr, 1024, DIMC);
    gemm_sp<0><<<dim3(32, 32), 256, 0, stream>>>(lat_h, lat_l, wkvu_h, wkvu_l, kvf, nullptr, nullptr, nullptr, 2048, RANKC);
    qknorm_rope_k<<<NTOK * NHEADS / 4, 256, 0, stream>>>(qf, kvf, q_nw, k_nw, qhi, qlo, khi, klo);
    transp_k<<<dim3(SEQC / 64, NHEADS, NBATCH), 256, 0, stream>>>(kvf, vthi, vtlo);
    flash_k<<<dim3(512), 256, 0, stream>>>(qhi, qlo, khi, klo, vthi, vtlo, ao_h, ao_l);
    gemm_sp<1><<<dim3(16, 32), 256, 0, stream>>>(ao_h, ao_l, wo_h, wo_l, h, nullptr, nullptr, x, DIMC, DIMC);
    rmsnorm_gate_k<<<NTOK, 256, 0, stream>>>(h, ffn_nw, xm_b, gate_w, topw, topi, plbuf);
    aux_red_k<<<16, 256, 0, stream>>>(plbuf, sums);
    route_k<<<1, 256, 0, stream>>>(topi, cnt, perm);
    moe_h_k<<<dim3(8, 32, 9), 256, 0, stream>>>(xm_b, ew1_b, sw1_b, perm, cnt, hid, s1_b);
    moe_c_k<<<dim3(16, 32, 8), 256, 0, stream>>>(hid, ew2_b, perm, cnt, yexp);
    gemm_fin<<<dim3(16, 32), 256, 0, stream>>>(s1_b, sw2_b, out, h, yexp, topw, DIMC, EHC);
    aux_k<<<1, 64, 0, stream>>>(sums, out + 4194304);
}